// Round 2
// baseline (688.163 us; speedup 1.0000x reference)
//
#include <hip/hip_runtime.h>
#include <hip/hip_bf16.h>
#include <math.h>

typedef __bf16 bf16;
typedef bf16 bf16x8 __attribute__((ext_vector_type(8)));
typedef float floatx4 __attribute__((ext_vector_type(4)));

#define NN 50000
#define EE 800000
#define DIMC 256
#define FFC 1024

typedef __attribute__((address_space(3))) unsigned int lds_u32;
typedef __attribute__((address_space(1))) unsigned int gbl_u32;

static __device__ __forceinline__ void glds16(const bf16* g, bf16* l) {
    __builtin_amdgcn_global_load_lds((const gbl_u32*)g, (lds_u32*)l, 16, 0, 0);
}

static __device__ __forceinline__ unsigned short f2b(float f) {
    bf16 b = (bf16)f;
    return __builtin_bit_cast(unsigned short, b);
}
static __device__ __forceinline__ float b2f_lo(unsigned u) { return __uint_as_float(u << 16); }
static __device__ __forceinline__ float b2f_hi(unsigned u) { return __uint_as_float(u & 0xffff0000u); }

// ---------------- elementwise cast fp32 -> bf16 (4 elems/thread) ----------------
__global__ __launch_bounds__(256)
void k_cast_bf16(const float* __restrict__ in, bf16* __restrict__ out, long n4) {
    long i = (long)blockIdx.x * 256 + threadIdx.x;
    if (i >= n4) return;
    float4 v = ((const float4*)in)[i];
    uint2 p;
    p.x = (unsigned)f2b(v.x) | ((unsigned)f2b(v.y) << 16);
    p.y = (unsigned)f2b(v.z) | ((unsigned)f2b(v.w) << 16);
    ((uint2*)out)[i] = p;
}

// ---------------- LDS-tiled transpose+cast: in [K][Nc] fp32 -> out [Nc][K] bf16 ----------------
__global__ __launch_bounds__(256)
void k_tcast(const float* __restrict__ in, bf16* __restrict__ out, int K, int Nc) {
    __shared__ float t[32][33];
    int n0 = blockIdx.x * 32, k0 = blockIdx.y * 32;
    int tx = threadIdx.x & 31, ty = threadIdx.x >> 5;  // ty 0..7
#pragma unroll
    for (int i = 0; i < 4; ++i)
        t[ty + i * 8][tx] = in[(long)(k0 + ty + i * 8) * Nc + n0 + tx];
    __syncthreads();
#pragma unroll
    for (int i = 0; i < 4; ++i)
        out[(long)(n0 + ty + i * 8) * K + k0 + tx] = (bf16)t[tx][ty + i * 8];
}

// ---------------- bf16 MFMA GEMM v2: C[M][Nc] = A[M][K] * BT[Nc][K]^T ----------------
// A strip [128 x 256-chunk] staged once per chunk in LDS (k-blocked layout);
// B fragments read directly from global (weights are L2-resident). Barrier-free inner loop.
// EPI 0: store bf16.  EPI 1: +bias, tanh-GELU, store bf16.  EPI 2: +bias, store bf16.
template <int EPI>
__global__ __launch_bounds__(256, 2)
void k_gemm2(const bf16* __restrict__ A, const bf16* __restrict__ BT,
             bf16* __restrict__ C, const float* __restrict__ bias,
             int M, int K, int Nc) {
    // blocked LDS: [chunk c 0..7][row 0..127][k 0..31] bf16 = 64KB; row stride 64B -> 2-way (free)
    __shared__ __attribute__((aligned(16))) bf16 As[8 * 128 * 32];
    const int tid = threadIdx.x;
    const int w = tid >> 6, lane = tid & 63;
    const int gm = blockIdx.x * 128, gn = blockIdx.y * 128;
    const int wm = (w >> 1) * 64, wn = (w & 1) * 64;
    const int lr = lane & 15, lk = (lane >> 4) * 8;
    const int rlane = lane >> 2, klane = (lane & 3) * 8;

    floatx4 acc[4][4];
#pragma unroll
    for (int a = 0; a < 4; ++a)
#pragma unroll
        for (int b = 0; b < 4; ++b) acc[a][b] = floatx4{0.f, 0.f, 0.f, 0.f};

    const int nchunk = K >> 8;
    for (int cs = 0; cs < nchunk; ++cs) {
        const int ks = cs << 8;
        if (cs) __syncthreads();  // protect LDS reuse
        // stage A[gm..gm+128][ks..ks+256]: 64 slots of 1KB; wave w does slots w*16..w*16+15
#pragma unroll
        for (int j = 0; j < 16; ++j) {
            int s = w * 16 + j;
            int c = s & 7, rg = s >> 3;
            int grow = min(gm + rg * 16 + rlane, M - 1);
            glds16(A + (long)grow * K + ks + c * 32 + klane,
                   As + c * 4096 + rg * 512 + lane * 8);
        }
        __syncthreads();
        // barrier-free MFMA loop: B frags straight from global (L2 hit)
#pragma unroll
        for (int kk = 0; kk < 8; ++kk) {
            bf16x8 af[4], bv[4];
            const bf16* Ab = As + kk * 4096;
#pragma unroll
            for (int ni = 0; ni < 4; ++ni)
                bv[ni] = *(const bf16x8*)(BT + (long)(gn + wn + ni * 16 + lr) * K + ks + kk * 32 + lk);
#pragma unroll
            for (int mi = 0; mi < 4; ++mi)
                af[mi] = *(const bf16x8*)(Ab + (wm + mi * 16 + lr) * 32 + lk);
#pragma unroll
            for (int mi = 0; mi < 4; ++mi)
#pragma unroll
                for (int ni = 0; ni < 4; ++ni)
                    acc[mi][ni] = __builtin_amdgcn_mfma_f32_16x16x32_bf16(af[mi], bv[ni], acc[mi][ni], 0, 0, 0);
        }
    }

    const int cr = (lane >> 4) * 4, cc = lane & 15;
#pragma unroll
    for (int ni = 0; ni < 4; ++ni) {
        const int col = gn + wn + ni * 16 + cc;
        const float bvs = (EPI != 0) ? bias[col] : 0.f;
#pragma unroll
        for (int mi = 0; mi < 4; ++mi) {
#pragma unroll
            for (int i = 0; i < 4; ++i) {
                const int row = gm + wm + mi * 16 + cr + i;
                if (row < M) {
                    float v = acc[mi][ni][i] + bvs;
                    if (EPI == 1) {
                        // tanh-approx GELU: v * sigmoid(1.5957691216*(v + 0.044715 v^3))*... == v/(1+exp(z))
                        float z = -1.5957691216f * v - 0.0713548163f * v * v * v;
                        v = v / (1.f + __expf(z));
                    }
                    C[(long)row * Nc + col] = (bf16)v;
                }
            }
        }
    }
}

// ---------------- per-node attention logits: alpha_src/dst [NN][4] ----------------
__global__ __launch_bounds__(256)
void k_alpha(const bf16* __restrict__ hb, const float* __restrict__ avs,
             const float* __restrict__ avd, float* __restrict__ asrc,
             float* __restrict__ adst) {
    int node = (blockIdx.x * 256 + threadIdx.x) >> 6;
    int lane = threadIdx.x & 63;
    if (node >= NN) return;
    int c = lane * 4;  // == head*64 + (lane&15)*4, head = lane>>4
    uint2 u = *(const uint2*)(hb + (long)node * DIMC + c);
    float h0 = b2f_lo(u.x), h1 = b2f_hi(u.x), h2 = b2f_lo(u.y), h3 = b2f_hi(u.y);
    float4 s4 = *(const float4*)(avs + c);
    float4 d4 = *(const float4*)(avd + c);
    float ds = h0 * s4.x + h1 * s4.y + h2 * s4.z + h3 * s4.w;
    float dd = h0 * d4.x + h1 * d4.y + h2 * d4.z + h3 * d4.w;
    for (int off = 1; off < 16; off <<= 1) { ds += __shfl_xor(ds, off); dd += __shfl_xor(dd, off); }
    if ((lane & 15) == 0) {
        int head = lane >> 4;
        asrc[node * 4 + head] = ds;
        adst[node * 4 + head] = dd;
    }
}

// ---------------- CSR build ----------------
__global__ __launch_bounds__(256)
void k_count(const int* __restrict__ dst, unsigned* __restrict__ deg) {
    int e = blockIdx.x * 256 + threadIdx.x;
    if (e < EE) atomicAdd(&deg[dst[e]], 1u);
}

__global__ __launch_bounds__(1024)
void k_scan(const unsigned* __restrict__ deg, unsigned* __restrict__ rowoff,
            unsigned* __restrict__ cursor) {
    __shared__ unsigned wsum[16], wscan[16];
    __shared__ unsigned carry;
    int tid = threadIdx.x, lane = tid & 63, wid = tid >> 6;
    if (tid == 0) carry = 0;
    __syncthreads();
    for (int base = 0; base < NN; base += 1024) {
        int i = base + tid;
        unsigned v = (i < NN) ? deg[i] : 0u;
        unsigned s = v;
        for (int off = 1; off < 64; off <<= 1) {
            unsigned t = __shfl_up(s, off);
            if (lane >= off) s += t;
        }
        if (lane == 63) wsum[wid] = s;
        __syncthreads();
        if (wid == 0) {
            unsigned t = (lane < 16) ? wsum[lane] : 0u;
            unsigned ts = t;
            for (int off = 1; off < 16; off <<= 1) {
                unsigned u2 = __shfl_up(ts, off);
                if (lane >= off) ts += u2;
            }
            if (lane < 16) wscan[lane] = ts;
        }
        __syncthreads();
        unsigned basew = (wid > 0) ? wscan[wid - 1] : 0u;
        unsigned excl = carry + basew + (s - v);
        if (i < NN) { rowoff[i] = excl; cursor[i] = excl; }
        __syncthreads();
        if (tid == 0) carry += wscan[15];
        __syncthreads();
    }
    if (tid == 0) rowoff[NN] = carry;
}

__global__ __launch_bounds__(256)
void k_fill(const int* __restrict__ src, const int* __restrict__ dst,
            unsigned* __restrict__ cursor, unsigned* __restrict__ elist) {
    int e = blockIdx.x * 256 + threadIdx.x;
    if (e < EE) {
        unsigned p = atomicAdd(&cursor[dst[e]], 1u);
        elist[p] = (unsigned)src[e];
    }
}

// ---------------- per-node: softmax-denom + gather-aggregate + residual + LN1 ----------------
__global__ __launch_bounds__(256)
void k_agg_ln1(const unsigned* __restrict__ rowoff, const unsigned* __restrict__ elist,
               const float* __restrict__ asrc, const float* __restrict__ adst,
               const bf16* __restrict__ hb, const float* __restrict__ x,
               const float* __restrict__ gatb, const float* __restrict__ lng,
               const float* __restrict__ lnb, bf16* __restrict__ x1b) {
    int node = (blockIdx.x * 256 + threadIdx.x) >> 6;
    int lane = threadIdx.x & 63;
    if (node >= NN) return;
    int beg = (int)rowoff[node], end = (int)rowoff[node + 1];
    int head = lane >> 4;
    float ad = adst[node * 4 + head];
    // pass 1: softmax denominator per head (no max-shift; logits bounded)
    float dsum = 0.f;
    for (int j = beg + (lane & 15); j < end; j += 16) {
        int s = (int)elist[j];
        float e = asrc[s * 4 + head] + ad;
        e = (e > 0.f) ? e : 0.2f * e;
        dsum += __expf(e);
    }
    dsum += __shfl_xor(dsum, 1);
    dsum += __shfl_xor(dsum, 2);
    dsum += __shfl_xor(dsum, 4);
    dsum += __shfl_xor(dsum, 8);
    float invd = 1.f / (dsum + 1e-16f);
    // pass 2: gather h[src] * alpha
    int c = lane * 4;
    float a0 = 0.f, a1 = 0.f, a2 = 0.f, a3 = 0.f;
    for (int j = beg; j < end; ++j) {
        int s = (int)elist[j];
        float e = asrc[s * 4 + head] + ad;
        e = (e > 0.f) ? e : 0.2f * e;
        float al = __expf(e) * invd;
        uint2 u = *(const uint2*)(hb + (long)s * DIMC + c);
        a0 += al * b2f_lo(u.x);
        a1 += al * b2f_hi(u.x);
        a2 += al * b2f_lo(u.y);
        a3 += al * b2f_hi(u.y);
    }
    // + x + gat_b, then LayerNorm across the row (4 vals/lane x 64 lanes)
    long base = (long)node * DIMC + c;
    float4 xr = *(const float4*)(x + base);
    float4 gb = *(const float4*)(gatb + c);
    float v0 = xr.x + a0 + gb.x;
    float v1 = xr.y + a1 + gb.y;
    float v2 = xr.z + a2 + gb.z;
    float v3 = xr.w + a3 + gb.w;
    float s1 = v0 + v1 + v2 + v3;
    float s2 = v0 * v0 + v1 * v1 + v2 * v2 + v3 * v3;
    for (int off = 1; off < 64; off <<= 1) { s1 += __shfl_xor(s1, off); s2 += __shfl_xor(s2, off); }
    float mu = s1 * (1.f / DIMC);
    float rs = rsqrtf(s2 * (1.f / DIMC) - mu * mu + 1e-5f);
    float4 g4 = *(const float4*)(lng + c);
    float4 b4 = *(const float4*)(lnb + c);
    float y0 = (v0 - mu) * rs * g4.x + b4.x;
    float y1 = (v1 - mu) * rs * g4.y + b4.y;
    float y2 = (v2 - mu) * rs * g4.z + b4.z;
    float y3 = (v3 - mu) * rs * g4.w + b4.w;
    uint2 p;
    p.x = (unsigned)f2b(y0) | ((unsigned)f2b(y1) << 16);
    p.y = (unsigned)f2b(y2) | ((unsigned)f2b(y3) << 16);
    *(uint2*)(x1b + base) = p;
}

// ---------------- x1 + ffn(bf16) -> LN2 -> + residual(x) -> out ----------------
__global__ __launch_bounds__(256)
void k_fuse2(const bf16* __restrict__ x1b, const bf16* __restrict__ ffn,
             const float* __restrict__ x, const float* __restrict__ lng,
             const float* __restrict__ lnb, float* __restrict__ out) {
    int node = (blockIdx.x * 256 + threadIdx.x) >> 6;
    int lane = threadIdx.x & 63;
    if (node >= NN) return;
    int c = lane * 4;
    long base = (long)node * DIMC + c;
    uint2 u = *(const uint2*)(x1b + base);
    uint2 f = *(const uint2*)(ffn + base);
    float v0 = b2f_lo(u.x) + b2f_lo(f.x);
    float v1 = b2f_hi(u.x) + b2f_hi(f.x);
    float v2 = b2f_lo(u.y) + b2f_lo(f.y);
    float v3 = b2f_hi(u.y) + b2f_hi(f.y);
    float s1 = v0 + v1 + v2 + v3;
    float s2 = v0 * v0 + v1 * v1 + v2 * v2 + v3 * v3;
    for (int off = 1; off < 64; off <<= 1) { s1 += __shfl_xor(s1, off); s2 += __shfl_xor(s2, off); }
    float mu = s1 * (1.f / DIMC);
    float rs = rsqrtf(s2 * (1.f / DIMC) - mu * mu + 1e-5f);
    float4 g4 = *(const float4*)(lng + c);
    float4 b4 = *(const float4*)(lnb + c);
    float4 xr = *(const float4*)(x + base);
    float4 o;
    o.x = (v0 - mu) * rs * g4.x + b4.x + xr.x;
    o.y = (v1 - mu) * rs * g4.y + b4.y + xr.y;
    o.z = (v2 - mu) * rs * g4.z + b4.z + xr.z;
    o.w = (v3 - mu) * rs * g4.w + b4.w + xr.w;
    *(float4*)(out + base) = o;
}

extern "C" void kernel_launch(void* const* d_in, const int* in_sizes, int n_in,
                              void* d_out, int out_size, void* d_ws, size_t ws_size,
                              hipStream_t stream) {
    const float* x    = (const float*)d_in[0];
    const int*   ei   = (const int*)d_in[1];
    const float* W    = (const float*)d_in[2];
    const float* a_s  = (const float*)d_in[3];
    const float* a_d  = (const float*)d_in[4];
    const float* gatb = (const float*)d_in[5];
    const float* lng  = (const float*)d_in[6];
    const float* lnb  = (const float*)d_in[7];
    const float* W1   = (const float*)d_in[8];
    const float* b1   = (const float*)d_in[9];
    const float* W2   = (const float*)d_in[10];
    const float* b2   = (const float*)d_in[11];
    float* out = (float*)d_out;
    char* ws = (char*)d_ws;

    // workspace layout (bytes, 256-aligned); total ~185.8 MB
    bf16*     xb     = (bf16*)(ws + 0L);           // 25.6 MB, dead after gemm1
    bf16*     hb     = (bf16*)(ws + 25600000L);    // 25.6 MB, dead after agg
    bf16*     x1b    = (bf16*)(ws + 51200000L);    // 25.6 MB
    bf16*     act    = (bf16*)(ws + 76800000L);    // 102.4 MB
    float*    asrc   = (float*)(ws + 179200000L);  // 0.8 MB
    float*    adst   = (float*)(ws + 180000000L);  // 0.8 MB
    unsigned* deg    = (unsigned*)(ws + 180800000L);
    unsigned* cursor = (unsigned*)(ws + 181000192L);
    unsigned* rowoff = (unsigned*)(ws + 181200384L);
    unsigned* elist  = (unsigned*)(ws + 181400832L);  // 3.2 MB
    bf16*     WT     = (bf16*)(ws + 184600832L);
    bf16*     W1T    = (bf16*)(ws + 184731904L);
    bf16*     W2T    = (bf16*)(ws + 185256192L);
    bf16*     ffn    = (bf16*)(ws + 0L);           // 25.6 MB, aliases xb (dead)

    const int* esrc = ei;
    const int* edst = ei + EE;

    hipMemsetAsync(deg, 0, NN * sizeof(unsigned), stream);
    k_cast_bf16<<<12500, 256, 0, stream>>>(x, xb, (long)NN * DIMC / 4);
    {
        dim3 gw(DIMC / 32, DIMC / 32);
        k_tcast<<<gw, 256, 0, stream>>>(W, WT, DIMC, DIMC);
        dim3 gw1(FFC / 32, DIMC / 32);
        k_tcast<<<gw1, 256, 0, stream>>>(W1, W1T, DIMC, FFC);
        dim3 gw2(DIMC / 32, FFC / 32);
        k_tcast<<<gw2, 256, 0, stream>>>(W2, W2T, FFC, DIMC);
    }

    dim3 g1(391, 2);
    k_gemm2<0><<<g1, 256, 0, stream>>>(xb, WT, hb, nullptr, NN, DIMC, DIMC);
    k_alpha<<<12500, 256, 0, stream>>>(hb, a_s, a_d, asrc, adst);

    k_count<<<3125, 256, 0, stream>>>(edst, deg);
    k_scan<<<1, 1024, 0, stream>>>(deg, rowoff, cursor);
    k_fill<<<3125, 256, 0, stream>>>(esrc, edst, cursor, elist);

    k_agg_ln1<<<12500, 256, 0, stream>>>(rowoff, elist, asrc, adst, hb, x, gatb, lng, lnb, x1b);

    dim3 g2(391, 8);
    k_gemm2<1><<<g2, 256, 0, stream>>>(x1b, W1T, act, b1, NN, DIMC, FFC);
    dim3 g3(391, 2);
    k_gemm2<2><<<g3, 256, 0, stream>>>(act, W2T, ffn, b2, NN, FFC, DIMC);

    k_fuse2<<<12500, 256, 0, stream>>>(x1b, ffn, x, lng, lnb, out);
}

// Round 3
// 580.113 us; speedup vs baseline: 1.1863x; 1.1863x over previous
//
#include <hip/hip_runtime.h>
#include <hip/hip_bf16.h>
#include <math.h>

typedef __bf16 bf16;
typedef bf16 bf16x8 __attribute__((ext_vector_type(8)));
typedef float floatx4 __attribute__((ext_vector_type(4)));

#define NN 50000
#define EE 800000
#define DIMC 256
#define FFC 1024

typedef __attribute__((address_space(3))) unsigned int lds_u32;
typedef __attribute__((address_space(1))) unsigned int gbl_u32;

static __device__ __forceinline__ void glds16(const bf16* g, bf16* l) {
    __builtin_amdgcn_global_load_lds((const gbl_u32*)g, (lds_u32*)l, 16, 0, 0);
}

static __device__ __forceinline__ unsigned short f2b(float f) {
    bf16 b = (bf16)f;
    return __builtin_bit_cast(unsigned short, b);
}
static __device__ __forceinline__ float b2f_lo(unsigned u) { return __uint_as_float(u << 16); }
static __device__ __forceinline__ float b2f_hi(unsigned u) { return __uint_as_float(u & 0xffff0000u); }

// ---------------- elementwise cast fp32 -> bf16 (4 elems/thread) ----------------
__global__ __launch_bounds__(256)
void k_cast_bf16(const float* __restrict__ in, bf16* __restrict__ out, long n4) {
    long i = (long)blockIdx.x * 256 + threadIdx.x;
    if (i >= n4) return;
    float4 v = ((const float4*)in)[i];
    uint2 p;
    p.x = (unsigned)f2b(v.x) | ((unsigned)f2b(v.y) << 16);
    p.y = (unsigned)f2b(v.z) | ((unsigned)f2b(v.w) << 16);
    ((uint2*)out)[i] = p;
}

// ---------------- LDS-tiled transpose+cast: in [K][Nc] fp32 -> out [Nc][K] bf16 ----------------
__global__ __launch_bounds__(256)
void k_tcast(const float* __restrict__ in, bf16* __restrict__ out, int K, int Nc) {
    __shared__ float t[32][33];
    int n0 = blockIdx.x * 32, k0 = blockIdx.y * 32;
    int tx = threadIdx.x & 31, ty = threadIdx.x >> 5;  // ty 0..7
#pragma unroll
    for (int i = 0; i < 4; ++i)
        t[ty + i * 8][tx] = in[(long)(k0 + ty + i * 8) * Nc + n0 + tx];
    __syncthreads();
#pragma unroll
    for (int i = 0; i < 4; ++i)
        out[(long)(n0 + ty + i * 8) * K + k0 + tx] = (bf16)t[tx][ty + i * 8];
}

// ---------------- bf16 MFMA GEMM v3: C[M][Nc] = A[M][K] * BT[Nc][K]^T ----------------
// BK=64, A+B tiles in LDS (32KB), XOR-swizzled 16B k-chunks (bank-conflict-free),
// two-barrier K-loop (R1 structure, 4 iters at K=256).
// EPI 0: store bf16.  EPI 1: +bias, sigmoid-GELU, store bf16.  EPI 2: +bias, store bf16.
template <int EPI>
__global__ __launch_bounds__(256)
void k_gemm3(const bf16* __restrict__ A, const bf16* __restrict__ BT,
             bf16* __restrict__ C, const float* __restrict__ bias,
             int M, int K, int Nc) {
    // layout: [row 0..127][k 0..63] bf16, row stride 128B; k-chunk c (16B) at row r
    // holds global chunk c ^ (r&7)
    __shared__ __attribute__((aligned(16))) bf16 As[128 * 64];
    __shared__ __attribute__((aligned(16))) bf16 Bs[128 * 64];
    const int tid = threadIdx.x;
    const int w = tid >> 6, lane = tid & 63;
    const int gm = blockIdx.x * 128, gn = blockIdx.y * 128;
    const int wm = (w >> 1) * 64, wn = (w & 1) * 64;
    const int lr = lane & 15, lkc = lane >> 4;  // fragment row-in-tile, k-chunk base (16B units)

    // staging: 16 slots of 1KB per matrix; slot s = rows s*8..s*8+7; wave w stages slots w*4..w*4+3.
    // lane l -> LDS byte slot*1024 + l*16  ==  row s*8 + (l>>3), chunk l&7.
    long aoff[4], boff[4];
#pragma unroll
    for (int j = 0; j < 4; ++j) {
        int s = w * 4 + j;
        int r = s * 8 + (lane >> 3);
        int kc = ((lane & 7) ^ (r & 7)) * 8;  // swizzled global k-element offset
        aoff[j] = (long)min(gm + r, M - 1) * K + kc;
        boff[j] = (long)(gn + r) * K + kc;
    }

    floatx4 acc[4][4];
#pragma unroll
    for (int a = 0; a < 4; ++a)
#pragma unroll
        for (int b = 0; b < 4; ++b) acc[a][b] = floatx4{0.f, 0.f, 0.f, 0.f};

    for (int k0 = 0; k0 < K; k0 += 64) {
        if (k0) __syncthreads();
#pragma unroll
        for (int j = 0; j < 4; ++j) {
            int s = w * 4 + j;
            glds16(A + aoff[j] + k0, As + s * 512);
            glds16(BT + boff[j] + k0, Bs + s * 512);
        }
        __syncthreads();
#pragma unroll
        for (int kk = 0; kk < 2; ++kk) {
            bf16x8 af[4], bv[4];
#pragma unroll
            for (int mi = 0; mi < 4; ++mi) {
                int r = wm + mi * 16 + lr;
                int ch = (kk * 4 + lkc) ^ (r & 7);
                af[mi] = *(const bf16x8*)(As + r * 64 + ch * 8);
            }
#pragma unroll
            for (int ni = 0; ni < 4; ++ni) {
                int r = wn + ni * 16 + lr;
                int ch = (kk * 4 + lkc) ^ (r & 7);
                bv[ni] = *(const bf16x8*)(Bs + r * 64 + ch * 8);
            }
#pragma unroll
            for (int mi = 0; mi < 4; ++mi)
#pragma unroll
                for (int ni = 0; ni < 4; ++ni)
                    acc[mi][ni] = __builtin_amdgcn_mfma_f32_16x16x32_bf16(af[mi], bv[ni], acc[mi][ni], 0, 0, 0);
        }
    }

    const int cr = (lane >> 4) * 4, cc = lane & 15;
#pragma unroll
    for (int ni = 0; ni < 4; ++ni) {
        const int col = gn + wn + ni * 16 + cc;
        const float bvs = (EPI != 0) ? bias[col] : 0.f;
#pragma unroll
        for (int mi = 0; mi < 4; ++mi) {
#pragma unroll
            for (int i = 0; i < 4; ++i) {
                const int row = gm + wm + mi * 16 + cr + i;
                if (row < M) {
                    float v = acc[mi][ni][i] + bvs;
                    if (EPI == 1) {
                        // tanh-GELU == v * sigmoid(1.5957691*(v + 0.044715 v^3))
                        float z = -1.5957691216f * v - 0.0713548163f * v * v * v;
                        v = v / (1.f + __expf(z));
                    }
                    C[(long)row * Nc + col] = (bf16)v;
                }
            }
        }
    }
}

// ---------------- per-node attention logits: alpha_src/dst [NN][4] ----------------
__global__ __launch_bounds__(256)
void k_alpha(const bf16* __restrict__ hb, const float* __restrict__ avs,
             const float* __restrict__ avd, float* __restrict__ asrc,
             float* __restrict__ adst) {
    int node = (blockIdx.x * 256 + threadIdx.x) >> 6;
    int lane = threadIdx.x & 63;
    if (node >= NN) return;
    int c = lane * 4;  // == head*64 + (lane&15)*4, head = lane>>4
    uint2 u = *(const uint2*)(hb + (long)node * DIMC + c);
    float h0 = b2f_lo(u.x), h1 = b2f_hi(u.x), h2 = b2f_lo(u.y), h3 = b2f_hi(u.y);
    float4 s4 = *(const float4*)(avs + c);
    float4 d4 = *(const float4*)(avd + c);
    float ds = h0 * s4.x + h1 * s4.y + h2 * s4.z + h3 * s4.w;
    float dd = h0 * d4.x + h1 * d4.y + h2 * d4.z + h3 * d4.w;
    for (int off = 1; off < 16; off <<= 1) { ds += __shfl_xor(ds, off); dd += __shfl_xor(dd, off); }
    if ((lane & 15) == 0) {
        int head = lane >> 4;
        asrc[node * 4 + head] = ds;
        adst[node * 4 + head] = dd;
    }
}

// ---------------- CSR build ----------------
__global__ __launch_bounds__(256)
void k_count(const int* __restrict__ dst, unsigned* __restrict__ deg) {
    int e = blockIdx.x * 256 + threadIdx.x;
    if (e < EE) atomicAdd(&deg[dst[e]], 1u);
}

__global__ __launch_bounds__(1024)
void k_scan(const unsigned* __restrict__ deg, unsigned* __restrict__ rowoff,
            unsigned* __restrict__ cursor) {
    __shared__ unsigned wsum[16], wscan[16];
    __shared__ unsigned carry;
    int tid = threadIdx.x, lane = tid & 63, wid = tid >> 6;
    if (tid == 0) carry = 0;
    __syncthreads();
    for (int base = 0; base < NN; base += 1024) {
        int i = base + tid;
        unsigned v = (i < NN) ? deg[i] : 0u;
        unsigned s = v;
        for (int off = 1; off < 64; off <<= 1) {
            unsigned t = __shfl_up(s, off);
            if (lane >= off) s += t;
        }
        if (lane == 63) wsum[wid] = s;
        __syncthreads();
        if (wid == 0) {
            unsigned t = (lane < 16) ? wsum[lane] : 0u;
            unsigned ts = t;
            for (int off = 1; off < 16; off <<= 1) {
                unsigned u2 = __shfl_up(ts, off);
                if (lane >= off) ts += u2;
            }
            if (lane < 16) wscan[lane] = ts;
        }
        __syncthreads();
        unsigned basew = (wid > 0) ? wscan[wid - 1] : 0u;
        unsigned excl = carry + basew + (s - v);
        if (i < NN) { rowoff[i] = excl; cursor[i] = excl; }
        __syncthreads();
        if (tid == 0) carry += wscan[15];
        __syncthreads();
    }
    if (tid == 0) rowoff[NN] = carry;
}

__global__ __launch_bounds__(256)
void k_fill(const int* __restrict__ src, const int* __restrict__ dst,
            unsigned* __restrict__ cursor, unsigned* __restrict__ elist) {
    int e = blockIdx.x * 256 + threadIdx.x;
    if (e < EE) {
        unsigned p = atomicAdd(&cursor[dst[e]], 1u);
        elist[p] = (unsigned)src[e];
    }
}

// ---------------- per-node: softmax-denom + gather-aggregate + residual + LN1 ----------------
__global__ __launch_bounds__(256)
void k_agg_ln1(const unsigned* __restrict__ rowoff, const unsigned* __restrict__ elist,
               const float* __restrict__ asrc, const float* __restrict__ adst,
               const bf16* __restrict__ hb, const float* __restrict__ x,
               const float* __restrict__ gatb, const float* __restrict__ lng,
               const float* __restrict__ lnb, bf16* __restrict__ x1b) {
    int node = (blockIdx.x * 256 + threadIdx.x) >> 6;
    int lane = threadIdx.x & 63;
    if (node >= NN) return;
    int beg = (int)rowoff[node], end = (int)rowoff[node + 1];
    int head = lane >> 4;
    float ad = adst[node * 4 + head];
    // pass 1: softmax denominator per head (no max-shift; logits bounded)
    float dsum = 0.f;
    for (int j = beg + (lane & 15); j < end; j += 16) {
        int s = (int)elist[j];
        float e = asrc[s * 4 + head] + ad;
        e = (e > 0.f) ? e : 0.2f * e;
        dsum += __expf(e);
    }
    dsum += __shfl_xor(dsum, 1);
    dsum += __shfl_xor(dsum, 2);
    dsum += __shfl_xor(dsum, 4);
    dsum += __shfl_xor(dsum, 8);
    float invd = 1.f / (dsum + 1e-16f);
    // pass 2: gather h[src] * alpha
    int c = lane * 4;
    float a0 = 0.f, a1 = 0.f, a2 = 0.f, a3 = 0.f;
    for (int j = beg; j < end; ++j) {
        int s = (int)elist[j];
        float e = asrc[s * 4 + head] + ad;
        e = (e > 0.f) ? e : 0.2f * e;
        float al = __expf(e) * invd;
        uint2 u = *(const uint2*)(hb + (long)s * DIMC + c);
        a0 += al * b2f_lo(u.x);
        a1 += al * b2f_hi(u.x);
        a2 += al * b2f_lo(u.y);
        a3 += al * b2f_hi(u.y);
    }
    // + x + gat_b, then LayerNorm across the row (4 vals/lane x 64 lanes)
    long base = (long)node * DIMC + c;
    float4 xr = *(const float4*)(x + base);
    float4 gb = *(const float4*)(gatb + c);
    float v0 = xr.x + a0 + gb.x;
    float v1 = xr.y + a1 + gb.y;
    float v2 = xr.z + a2 + gb.z;
    float v3 = xr.w + a3 + gb.w;
    float s1 = v0 + v1 + v2 + v3;
    float s2 = v0 * v0 + v1 * v1 + v2 * v2 + v3 * v3;
    for (int off = 1; off < 64; off <<= 1) { s1 += __shfl_xor(s1, off); s2 += __shfl_xor(s2, off); }
    float mu = s1 * (1.f / DIMC);
    float rs = rsqrtf(s2 * (1.f / DIMC) - mu * mu + 1e-5f);
    float4 g4 = *(const float4*)(lng + c);
    float4 b4 = *(const float4*)(lnb + c);
    float y0 = (v0 - mu) * rs * g4.x + b4.x;
    float y1 = (v1 - mu) * rs * g4.y + b4.y;
    float y2 = (v2 - mu) * rs * g4.z + b4.z;
    float y3 = (v3 - mu) * rs * g4.w + b4.w;
    uint2 p;
    p.x = (unsigned)f2b(y0) | ((unsigned)f2b(y1) << 16);
    p.y = (unsigned)f2b(y2) | ((unsigned)f2b(y3) << 16);
    *(uint2*)(x1b + base) = p;
}

// ---------------- x1 + ffn(bf16) -> LN2 -> + residual(x) -> out ----------------
__global__ __launch_bounds__(256)
void k_fuse2(const bf16* __restrict__ x1b, const bf16* __restrict__ ffn,
             const float* __restrict__ x, const float* __restrict__ lng,
             const float* __restrict__ lnb, float* __restrict__ out) {
    int node = (blockIdx.x * 256 + threadIdx.x) >> 6;
    int lane = threadIdx.x & 63;
    if (node >= NN) return;
    int c = lane * 4;
    long base = (long)node * DIMC + c;
    uint2 u = *(const uint2*)(x1b + base);
    uint2 f = *(const uint2*)(ffn + base);
    float v0 = b2f_lo(u.x) + b2f_lo(f.x);
    float v1 = b2f_hi(u.x) + b2f_hi(f.x);
    float v2 = b2f_lo(u.y) + b2f_lo(f.y);
    float v3 = b2f_hi(u.y) + b2f_hi(f.y);
    float s1 = v0 + v1 + v2 + v3;
    float s2 = v0 * v0 + v1 * v1 + v2 * v2 + v3 * v3;
    for (int off = 1; off < 64; off <<= 1) { s1 += __shfl_xor(s1, off); s2 += __shfl_xor(s2, off); }
    float mu = s1 * (1.f / DIMC);
    float rs = rsqrtf(s2 * (1.f / DIMC) - mu * mu + 1e-5f);
    float4 g4 = *(const float4*)(lng + c);
    float4 b4 = *(const float4*)(lnb + c);
    float4 xr = *(const float4*)(x + base);
    float4 o;
    o.x = (v0 - mu) * rs * g4.x + b4.x + xr.x;
    o.y = (v1 - mu) * rs * g4.y + b4.y + xr.y;
    o.z = (v2 - mu) * rs * g4.z + b4.z + xr.z;
    o.w = (v3 - mu) * rs * g4.w + b4.w + xr.w;
    *(float4*)(out + base) = o;
}

extern "C" void kernel_launch(void* const* d_in, const int* in_sizes, int n_in,
                              void* d_out, int out_size, void* d_ws, size_t ws_size,
                              hipStream_t stream) {
    const float* x    = (const float*)d_in[0];
    const int*   ei   = (const int*)d_in[1];
    const float* W    = (const float*)d_in[2];
    const float* a_s  = (const float*)d_in[3];
    const float* a_d  = (const float*)d_in[4];
    const float* gatb = (const float*)d_in[5];
    const float* lng  = (const float*)d_in[6];
    const float* lnb  = (const float*)d_in[7];
    const float* W1   = (const float*)d_in[8];
    const float* b1   = (const float*)d_in[9];
    const float* W2   = (const float*)d_in[10];
    const float* b2   = (const float*)d_in[11];
    float* out = (float*)d_out;
    char* ws = (char*)d_ws;

    // workspace layout (bytes, 256-aligned); total ~185.8 MB
    bf16*     xb     = (bf16*)(ws + 0L);           // 25.6 MB, dead after gemm1
    bf16*     hb     = (bf16*)(ws + 25600000L);    // 25.6 MB, dead after agg
    bf16*     x1b    = (bf16*)(ws + 51200000L);    // 25.6 MB
    bf16*     act    = (bf16*)(ws + 76800000L);    // 102.4 MB
    float*    asrc   = (float*)(ws + 179200000L);  // 0.8 MB
    float*    adst   = (float*)(ws + 180000000L);  // 0.8 MB
    unsigned* deg    = (unsigned*)(ws + 180800000L);
    unsigned* cursor = (unsigned*)(ws + 181000192L);
    unsigned* rowoff = (unsigned*)(ws + 181200384L);
    unsigned* elist  = (unsigned*)(ws + 181400832L);  // 3.2 MB
    bf16*     WT     = (bf16*)(ws + 184600832L);
    bf16*     W1T    = (bf16*)(ws + 184731904L);
    bf16*     W2T    = (bf16*)(ws + 185256192L);
    bf16*     ffn    = (bf16*)(ws + 0L);           // 25.6 MB, aliases xb (dead)

    const int* esrc = ei;
    const int* edst = ei + EE;

    hipMemsetAsync(deg, 0, NN * sizeof(unsigned), stream);
    k_cast_bf16<<<12500, 256, 0, stream>>>(x, xb, (long)NN * DIMC / 4);
    {
        dim3 gw(DIMC / 32, DIMC / 32);
        k_tcast<<<gw, 256, 0, stream>>>(W, WT, DIMC, DIMC);
        dim3 gw1(FFC / 32, DIMC / 32);
        k_tcast<<<gw1, 256, 0, stream>>>(W1, W1T, DIMC, FFC);
        dim3 gw2(DIMC / 32, FFC / 32);
        k_tcast<<<gw2, 256, 0, stream>>>(W2, W2T, FFC, DIMC);
    }

    dim3 g1(391, 2);
    k_gemm3<0><<<g1, 256, 0, stream>>>(xb, WT, hb, nullptr, NN, DIMC, DIMC);
    k_alpha<<<12500, 256, 0, stream>>>(hb, a_s, a_d, asrc, adst);

    k_count<<<3125, 256, 0, stream>>>(edst, deg);
    k_scan<<<1, 1024, 0, stream>>>(deg, rowoff, cursor);
    k_fill<<<3125, 256, 0, stream>>>(esrc, edst, cursor, elist);

    k_agg_ln1<<<12500, 256, 0, stream>>>(rowoff, elist, asrc, adst, hb, x, gatb, lng, lnb, x1b);

    dim3 g2(391, 8);
    k_gemm3<1><<<g2, 256, 0, stream>>>(x1b, W1T, act, b1, NN, DIMC, FFC);
    dim3 g3(391, 2);
    k_gemm3<2><<<g3, 256, 0, stream>>>(act, W2T, ffn, b2, NN, FFC, DIMC);

    k_fuse2<<<12500, 256, 0, stream>>>(x1b, ffn, x, lng, lnb, out);
}